// Round 1
// baseline (1478.888 us; speedup 1.0000x reference)
//
#include <hip/hip_runtime.h>

// Problem constants (fixed by the harness's setup_inputs)
#define NN 100000   // nodes
#define EE 1600000  // edges per relation
#define RR 4        // relations
#define FF 64       // feature size (in == out == 64)

// out[n][j] = sum_r bias[r][j]  (exactly N*F threads)
__global__ __launch_bounds__(256) void init_out_kernel(const float* __restrict__ bias,
                                                       float* __restrict__ out) {
    int i = blockIdx.x * 256 + threadIdx.x;   // grid sized exactly to N*F
    int j = i & (FF - 1);
    out[i] = bias[j] + bias[FF + j] + bias[2 * FF + j] + bias[3 * FF + j];
}

// Y[r][n][j] = sum_k inp[n][k] * W[r][k][j]
// Block: 256 threads = 4 waves, handles 64 rows of inp.
// NREL==4: wave w computes relation w for all 64 rows.
// NREL==1: all waves same relation (W pre-offset by host), wave w does 16 rows.
template <int NREL>
__global__ __launch_bounds__(256) void compute_y_kernel(const float* __restrict__ inp,
                                                        const float* __restrict__ W,
                                                        float* __restrict__ Y) {
    __shared__ float s_inp[64 * FF];

    const int row0  = blockIdx.x * 64;
    const int nrows = min(64, NN - row0);

    // Stage input rows into LDS with float4 loads (coalesced).
    {
        const float4* g  = reinterpret_cast<const float4*>(inp + (size_t)row0 * FF);
        float4*       s4 = reinterpret_cast<float4*>(s_inp);
        const int     nv4 = nrows * (FF / 4);
        for (int t = threadIdx.x; t < 64 * (FF / 4); t += 256) {
            s4[t] = (t < nv4) ? g[t] : make_float4(0.f, 0.f, 0.f, 0.f);
        }
    }
    __syncthreads();

    const int wid  = threadIdx.x >> 6;
    const int lane = threadIdx.x & 63;
    const int r    = (NREL == RR) ? wid : 0;

    // Weights column j=lane for relation r held in registers (64 VGPRs).
    float wreg[FF];
    {
        const float* Wr = W + (size_t)r * FF * FF + lane;
#pragma unroll
        for (int k = 0; k < FF; ++k) wreg[k] = Wr[(size_t)k * FF];
    }

    int rbeg, rend;
    if (NREL == RR) { rbeg = 0;        rend = nrows; }
    else            { rbeg = wid * 16; rend = min(wid * 16 + 16, nrows); }

    float* Yp = Y + ((size_t)r * NN + row0) * FF + lane;
    for (int row = rbeg; row < rend; ++row) {
        const float4* a4 = reinterpret_cast<const float4*>(s_inp + row * FF);
        float acc0 = 0.f, acc1 = 0.f, acc2 = 0.f, acc3 = 0.f;
#pragma unroll
        for (int k4 = 0; k4 < FF / 4; ++k4) {
            float4 a = a4[k4];  // uniform address across wave -> LDS broadcast
            acc0 = fmaf(a.x, wreg[4 * k4 + 0], acc0);
            acc1 = fmaf(a.y, wreg[4 * k4 + 1], acc1);
            acc2 = fmaf(a.z, wreg[4 * k4 + 2], acc2);
            acc3 = fmaf(a.w, wreg[4 * k4 + 3], acc3);
        }
        Yp[(size_t)row * FF] = (acc0 + acc1) + (acc2 + acc3);
    }
}

// One wave per edge: out[dst][lane] += val * Y[plane][src][lane]
template <bool MULTI>
__global__ __launch_bounds__(256) void edge_scatter_kernel(const int* __restrict__ src,
                                                           const int* __restrict__ dst,
                                                           const float* __restrict__ val,
                                                           const float* __restrict__ Y,
                                                           float* __restrict__ out,
                                                           int n_edges) {
    const int w = (blockIdx.x * 256 + threadIdx.x) >> 6;
    if (w >= n_edges) return;
    const int   lane  = threadIdx.x & 63;
    const int   s     = src[w];
    const int   d     = dst[w];
    const float v     = val[w];
    const int   plane = MULTI ? (w / EE) : 0;   // compiler magic-muls the const div
    const float y     = Y[((size_t)plane * NN + s) * FF + lane];
    atomicAdd(out + (size_t)d * FF + lane, v * y);
}

extern "C" void kernel_launch(void* const* d_in, const int* in_sizes, int n_in,
                              void* d_out, int out_size, void* d_ws, size_t ws_size,
                              hipStream_t stream) {
    const float* inp  = (const float*)d_in[0];
    const int*   src  = (const int*)d_in[1];
    const int*   dst  = (const int*)d_in[2];
    const float* val  = (const float*)d_in[3];
    const float* W    = (const float*)d_in[4];
    const float* bias = (const float*)d_in[5];
    float*       out  = (float*)d_out;
    float*       Y    = (float*)d_ws;

    // 1) out = summed bias
    init_out_kernel<<<(NN * FF) / 256, 256, 0, stream>>>(bias, out);

    const int yblocks = (NN + 63) / 64;
    const size_t y_all = (size_t)RR * NN * FF * sizeof(float);

    if (ws_size >= y_all) {
        // 2) Y[r] = inp @ W[r] for all relations at once
        compute_y_kernel<RR><<<yblocks, 256, 0, stream>>>(inp, W, Y);
        // 3) scatter all 6.4M edges, one wave per edge
        const int waves = RR * EE;
        edge_scatter_kernel<true><<<(waves + 3) / 4, 256, 0, stream>>>(src, dst, val, Y, out, waves);
    } else {
        // Fallback: relation-sequential, needs only N*F*4 = 25.6 MB of ws
        for (int r = 0; r < RR; ++r) {
            compute_y_kernel<1><<<yblocks, 256, 0, stream>>>(inp, W + (size_t)r * FF * FF, Y);
            edge_scatter_kernel<false><<<(EE + 3) / 4, 256, 0, stream>>>(
                src + (size_t)r * EE, dst + (size_t)r * EE, val + (size_t)r * EE, Y, out, EE);
        }
    }
}

// Round 2
// 949.668 us; speedup vs baseline: 1.5573x; 1.5573x over previous
//
#include <hip/hip_runtime.h>

// Problem constants (fixed by the harness's setup_inputs)
#define NN 100000   // nodes
#define EE 1600000  // edges per relation
#define RR 4        // relations
#define FF 64       // feature size (in == out == 64)
#define NEDGE (RR * EE)
#define SCAN_B ((NN + 255) / 256)   // 391 blocks for the scan

// ---------------------------------------------------------------------------
// Y[r][n][j] = sum_k inp[n][k] * W[r][k][j]
// Block: 256 threads = 4 waves, 64 rows of inp; wave w computes relation w.
template <int NREL>
__global__ __launch_bounds__(256) void compute_y_kernel(const float* __restrict__ inp,
                                                        const float* __restrict__ W,
                                                        float* __restrict__ Y) {
    __shared__ float s_inp[64 * FF];

    const int row0  = blockIdx.x * 64;
    const int nrows = min(64, NN - row0);

    {
        const float4* g  = reinterpret_cast<const float4*>(inp + (size_t)row0 * FF);
        float4*       s4 = reinterpret_cast<float4*>(s_inp);
        const int     nv4 = nrows * (FF / 4);
        for (int t = threadIdx.x; t < 64 * (FF / 4); t += 256) {
            s4[t] = (t < nv4) ? g[t] : make_float4(0.f, 0.f, 0.f, 0.f);
        }
    }
    __syncthreads();

    const int wid  = threadIdx.x >> 6;
    const int lane = threadIdx.x & 63;
    const int r    = (NREL == RR) ? wid : 0;

    float wreg[FF];
    {
        const float* Wr = W + (size_t)r * FF * FF + lane;
#pragma unroll
        for (int k = 0; k < FF; ++k) wreg[k] = Wr[(size_t)k * FF];
    }

    int rbeg, rend;
    if (NREL == RR) { rbeg = 0;        rend = nrows; }
    else            { rbeg = wid * 16; rend = min(wid * 16 + 16, nrows); }

    float* Yp = Y + ((size_t)r * NN + row0) * FF + lane;
    for (int row = rbeg; row < rend; ++row) {
        const float4* a4 = reinterpret_cast<const float4*>(s_inp + row * FF);
        float acc0 = 0.f, acc1 = 0.f, acc2 = 0.f, acc3 = 0.f;
#pragma unroll
        for (int k4 = 0; k4 < FF / 4; ++k4) {
            float4 a = a4[k4];  // wave-uniform address -> LDS broadcast
            acc0 = fmaf(a.x, wreg[4 * k4 + 0], acc0);
            acc1 = fmaf(a.y, wreg[4 * k4 + 1], acc1);
            acc2 = fmaf(a.z, wreg[4 * k4 + 2], acc2);
            acc3 = fmaf(a.w, wreg[4 * k4 + 3], acc3);
        }
        Yp[(size_t)row * FF] = (acc0 + acc1) + (acc2 + acc3);
    }
}

// ---------------------------------------------------------------------------
// Counting-sort pipeline
__global__ __launch_bounds__(256) void hist_kernel(const int* __restrict__ dst,
                                                   int* __restrict__ hist) {
    int e = blockIdx.x * 256 + threadIdx.x;
    if (e < NEDGE) atomicAdd(&hist[dst[e]], 1);
}

// Per-block exclusive scan; writes exclusive-in-block prefix + block totals.
__global__ __launch_bounds__(256) void scan1_kernel(const int* __restrict__ hist,
                                                    int* __restrict__ partial,
                                                    int* __restrict__ bsums) {
    __shared__ int s[256];
    const int tid = threadIdx.x;
    const int i   = blockIdx.x * 256 + tid;
    const int v   = (i < NN) ? hist[i] : 0;
    s[tid] = v;
    __syncthreads();
    for (int d = 1; d < 256; d <<= 1) {
        int t = (tid >= d) ? s[tid - d] : 0;
        __syncthreads();
        s[tid] += t;
        __syncthreads();
    }
    if (i < NN) partial[i] = s[tid] - v;           // exclusive within block
    if (tid == 255) bsums[blockIdx.x] = s[255];    // block total
}

// Single-block inclusive scan of the block totals.
__global__ __launch_bounds__(512) void scan2_kernel(int* __restrict__ bsums) {
    __shared__ int s[512];
    const int tid = threadIdx.x;
    s[tid] = (tid < SCAN_B) ? bsums[tid] : 0;
    __syncthreads();
    for (int d = 1; d < 512; d <<= 1) {
        int t = (tid >= d) ? s[tid - d] : 0;
        __syncthreads();
        s[tid] += t;
        __syncthreads();
    }
    if (tid < SCAN_B) bsums[tid] = s[tid];
}

// Final global exclusive offsets + mutable cursor copy.
__global__ __launch_bounds__(256) void scan3_kernel(const int* __restrict__ partial,
                                                    const int* __restrict__ bsums,
                                                    int* __restrict__ offsets,
                                                    int* __restrict__ cursor) {
    const int i = blockIdx.x * 256 + threadIdx.x;
    if (i >= NN) return;
    const int boff = (blockIdx.x > 0) ? bsums[blockIdx.x - 1] : 0;
    const int v    = partial[i] + boff;
    offsets[i] = v;
    cursor[i]  = v;
    if (i == 0) offsets[NN] = NEDGE;
}

// Scatter each edge's record {Y-row index, value} to its dst bucket.
__global__ __launch_bounds__(256) void scatter_kernel(const int* __restrict__ src,
                                                      const int* __restrict__ dst,
                                                      const float* __restrict__ val,
                                                      int* __restrict__ cursor,
                                                      int2* __restrict__ recs) {
    const int e = blockIdx.x * 256 + threadIdx.x;
    if (e >= NEDGE) return;
    const int d     = dst[e];
    const int plane = e / EE;                      // const-div -> magic mul
    const int pos   = atomicAdd(&cursor[d], 1);
    recs[pos] = make_int2(plane * NN + src[e], __float_as_int(val[e]));
}

// One wave per node: acc[lane] = sum_e val_e * Y[row_e][lane]; single store.
__global__ __launch_bounds__(256) void gather_kernel(const int* __restrict__ offsets,
                                                     const int2* __restrict__ recs,
                                                     const float* __restrict__ Y,
                                                     const float* __restrict__ bias,
                                                     float* __restrict__ out) {
    const int n = blockIdx.x * 4 + (threadIdx.x >> 6);
    if (n >= NN) return;
    const int lane = threadIdx.x & 63;
    const int beg  = offsets[n];
    const int end  = offsets[n + 1];

    float acc = 0.f;
    int e = beg;
    for (; e + 4 <= end; e += 4) {                 // 4 independent gathers -> MLP
        const int2 r0 = recs[e], r1 = recs[e + 1], r2 = recs[e + 2], r3 = recs[e + 3];
        const float y0 = Y[(size_t)r0.x * FF + lane];
        const float y1 = Y[(size_t)r1.x * FF + lane];
        const float y2 = Y[(size_t)r2.x * FF + lane];
        const float y3 = Y[(size_t)r3.x * FF + lane];
        acc = fmaf(__int_as_float(r0.y), y0, acc);
        acc = fmaf(__int_as_float(r1.y), y1, acc);
        acc = fmaf(__int_as_float(r2.y), y2, acc);
        acc = fmaf(__int_as_float(r3.y), y3, acc);
    }
    for (; e < end; ++e) {
        const int2 r = recs[e];
        acc = fmaf(__int_as_float(r.y), Y[(size_t)r.x * FF + lane], acc);
    }
    out[(size_t)n * FF + lane] =
        acc + bias[lane] + bias[FF + lane] + bias[2 * FF + lane] + bias[3 * FF + lane];
}

// ---------------------------------------------------------------------------
// Fallback path (round-1): atomic scatter straight to out.
__global__ __launch_bounds__(256) void init_out_kernel(const float* __restrict__ bias,
                                                       float* __restrict__ out) {
    int i = blockIdx.x * 256 + threadIdx.x;
    int j = i & (FF - 1);
    out[i] = bias[j] + bias[FF + j] + bias[2 * FF + j] + bias[3 * FF + j];
}

template <bool MULTI>
__global__ __launch_bounds__(256) void edge_scatter_kernel(const int* __restrict__ src,
                                                           const int* __restrict__ dst,
                                                           const float* __restrict__ val,
                                                           const float* __restrict__ Y,
                                                           float* __restrict__ out,
                                                           int n_edges) {
    const int w = (blockIdx.x * 256 + threadIdx.x) >> 6;
    if (w >= n_edges) return;
    const int   lane  = threadIdx.x & 63;
    const int   s     = src[w];
    const int   d     = dst[w];
    const float v     = val[w];
    const int   plane = MULTI ? (w / EE) : 0;
    const float y     = Y[((size_t)plane * NN + s) * FF + lane];
    atomicAdd(out + (size_t)d * FF + lane, v * y);
}

// ---------------------------------------------------------------------------
extern "C" void kernel_launch(void* const* d_in, const int* in_sizes, int n_in,
                              void* d_out, int out_size, void* d_ws, size_t ws_size,
                              hipStream_t stream) {
    const float* inp  = (const float*)d_in[0];
    const int*   src  = (const int*)d_in[1];
    const int*   dst  = (const int*)d_in[2];
    const float* val  = (const float*)d_in[3];
    const float* W    = (const float*)d_in[4];
    const float* bias = (const float*)d_in[5];
    float*       out  = (float*)d_out;
    char*        ws   = (char*)d_ws;

    // ws layout
    const size_t Y_OFF   = 0;
    const size_t Y_SZ    = (size_t)RR * NN * FF * sizeof(float);      // 102,400,000
    const size_t R_OFF   = Y_OFF + Y_SZ;                              // 8-aligned
    const size_t R_SZ    = (size_t)NEDGE * sizeof(int2);              // 51,200,000
    const size_t H_OFF   = R_OFF + R_SZ;
    const size_t H_SZ    = (size_t)NN * sizeof(int);
    const size_t P_OFF   = H_OFF + H_SZ;
    const size_t P_SZ    = (size_t)NN * sizeof(int);
    const size_t O_OFF   = P_OFF + P_SZ;
    const size_t O_SZ    = (size_t)(NN + 1) * sizeof(int);
    const size_t C_OFF   = O_OFF + O_SZ + 4;                          // keep 8-align
    const size_t C_SZ    = (size_t)NN * sizeof(int);
    const size_t B_OFF   = C_OFF + C_SZ;
    const size_t B_SZ    = (size_t)SCAN_B * sizeof(int);
    const size_t TOTAL   = B_OFF + B_SZ;                              // ~155.2 MB

    float* Y       = (float*)(ws + Y_OFF);
    int2*  recs    = (int2*)(ws + R_OFF);
    int*   hist    = (int*)(ws + H_OFF);
    int*   partial = (int*)(ws + P_OFF);
    int*   offsets = (int*)(ws + O_OFF);
    int*   cursor  = (int*)(ws + C_OFF);
    int*   bsums   = (int*)(ws + B_OFF);

    const int yblocks = (NN + 63) / 64;

    if (ws_size >= TOTAL) {
        // 1) Y[r] = inp @ W[r]
        compute_y_kernel<RR><<<yblocks, 256, 0, stream>>>(inp, W, Y);
        // 2) counting sort of edges by dst
        hipMemsetAsync(hist, 0, H_SZ, stream);
        hist_kernel<<<(NEDGE + 255) / 256, 256, 0, stream>>>(dst, hist);
        scan1_kernel<<<SCAN_B, 256, 0, stream>>>(hist, partial, bsums);
        scan2_kernel<<<1, 512, 0, stream>>>(bsums);
        scan3_kernel<<<SCAN_B, 256, 0, stream>>>(partial, bsums, offsets, cursor);
        scatter_kernel<<<(NEDGE + 255) / 256, 256, 0, stream>>>(src, dst, val, cursor, recs);
        // 3) conflict-free gather: one wave per node, single store
        gather_kernel<<<(NN + 3) / 4, 256, 0, stream>>>(offsets, recs, Y, bias, out);
    } else if (ws_size >= Y_SZ) {
        // Fallback: atomic scatter (round-1 path)
        init_out_kernel<<<(NN * FF) / 256, 256, 0, stream>>>(bias, out);
        compute_y_kernel<RR><<<yblocks, 256, 0, stream>>>(inp, W, Y);
        const int waves = NEDGE;
        edge_scatter_kernel<true><<<(waves + 3) / 4, 256, 0, stream>>>(src, dst, val, Y, out, waves);
    } else {
        // Last-resort: relation-sequential
        init_out_kernel<<<(NN * FF) / 256, 256, 0, stream>>>(bias, out);
        for (int r = 0; r < RR; ++r) {
            compute_y_kernel<1><<<yblocks, 256, 0, stream>>>(inp, W + (size_t)r * FF * FF, Y);
            edge_scatter_kernel<false><<<(EE + 3) / 4, 256, 0, stream>>>(
                src + (size_t)r * EE, dst + (size_t)r * EE, val + (size_t)r * EE, Y, out, EE);
        }
    }
}